// Round 4
// baseline (387.959 us; speedup 1.0000x reference)
//
#include <hip/hip_runtime.h>
#include <stdint.h>

// ---------------------------------------------------------------------------
// EmbraceNet fused: out[b,e] = relu(x_f @ W_f + b_f)[b,e],  f = idx[b,e]
// idx = categorical(key=42): partitionable threefry, bits = y0^y1 of
// threefry2x32((0,42), (0, (e*4096+b)*4+f)); argmax over bits>>9, strict >.
// PASS since R4 (absmax 0.031).
//
// R14: faithful m201 8-phase port. K-split by plane pair: block (m,n,ks)
// computes planes {2ks, 2ks+1}; selection fold = exec-masked direct stores
// (disjoint across ks -> no combine, no res regs). BM=BN=256, BK=64,
// 8 waves (2Mx4N, wave tile 128x64), 128KiB LDS double-buffer. Per K-tile
// 4 phases (khalf h x mi-half); per phase: {ds_read 4or8 x b128 -> stage 1
// half-tile (2 gload_lds) -> s_barrier -> lgkmcnt(0)+sched_barrier ->
// setprio(1) 16 MFMA setprio(0) -> s_barrier}. vmcnt(6) ONLY at tile
// boundaries (3 half-tiles in flight). Stage mapping (derived from read
// retirement): tile j: q0->(j+1,A,h1) q1->(j+2,B,h0) q2->(j+2,A,h0)
// q3->(j+2,B,h1); every stage >=1 barrier after its region's last read.
// LDS: per-khalf [256 rows][4 slots x16B], slot = chunk ^ ((row>>1)&3)
// (balanced 8 words/bank); pre-swizzled global src, linear LDS dst.
// ---------------------------------------------------------------------------

typedef short short8 __attribute__((ext_vector_type(8)));
typedef float floatx4 __attribute__((ext_vector_type(4)));

#define B_DIM 4096
#define K_DIM 1024
#define E_DIM 2048

__device__ __forceinline__ uint32_t rotl32(uint32_t x, uint32_t r) {
  return __builtin_amdgcn_alignbit(x, x, 32u - r);
}

__device__ __forceinline__ uint16_t f2bf(float x) {
  uint32_t u = __float_as_uint(x);
  u += 0x7FFFu + ((u >> 16) & 1u);
  return (uint16_t)(u >> 16);
}

// JAX threefry2x32, key = (0, 42)
__device__ __forceinline__ void threefry(uint32_t x0, uint32_t x1,
                                         uint32_t& o0, uint32_t& o1) {
  const uint32_t ks0 = 0u;
  const uint32_t ks1 = 42u;
  const uint32_t ks2 = 0x1BD11BDAu ^ 42u;
  x0 += ks0; x1 += ks1;
#define TF_R(r) { x0 += x1; x1 = rotl32(x1, r); x1 ^= x0; }
  TF_R(13) TF_R(15) TF_R(26) TF_R(6)
  x0 += ks1; x1 += ks2 + 1u;
  TF_R(17) TF_R(29) TF_R(16) TF_R(24)
  x0 += ks2; x1 += ks0 + 2u;
  TF_R(13) TF_R(15) TF_R(26) TF_R(6)
  x0 += ks0; x1 += ks1 + 3u;
  TF_R(17) TF_R(29) TF_R(16) TF_R(24)
  x0 += ks1; x1 += ks2 + 4u;
  TF_R(13) TF_R(15) TF_R(26) TF_R(6)
  x0 += ks2; x1 += ks0 + 5u;
#undef TF_R
  o0 = x0; o1 = x1;
}

// 8192 blocks x 256 threads. Unchanged since R10.
__global__ __launch_bounds__(256) void prep_kernel(
    const float* __restrict__ x0, const float* __restrict__ x1,
    const float* __restrict__ x2, const float* __restrict__ x3,
    const float* __restrict__ W0, const float* __restrict__ W1,
    const float* __restrict__ W2, const float* __restrict__ W3,
    uint16_t* __restrict__ xb, uint16_t* __restrict__ Wt,
    uint8_t* __restrict__ idx1) {
  __shared__ float tile[32][33];
  const uint32_t g = blockIdx.x;       // 0..8191
  const int t = threadIdx.x;
  const int f = g >> 11;               // plane 0..3
  const uint32_t ip = g & 2047u;       // tile/chunk within plane

  const float* x = (f == 0) ? x0 : (f == 1) ? x1 : (f == 2) ? x2 : x3;
  const size_t xoff = ((size_t)ip * 256 + t) * 8;
  float4 v0 = *(const float4*)(x + xoff);
  float4 v1 = *(const float4*)(x + xoff + 4);

  const float* W = (f == 0) ? W0 : (f == 1) ? W1 : (f == 2) ? W2 : W3;
  const int e0 = (int)(ip & 63) * 32, k0 = (int)(ip >> 6) * 32;
  const int tx = t & 31, ty = t >> 5;
  float wv[4];
#pragma unroll
  for (int i = 0; i < 4; ++i)
    wv[i] = W[(size_t)(k0 + ty + i * 8) * E_DIM + e0 + tx];

  const uint32_t o0i = (g * 256u + t) * 4u;
  uint32_t byte = 0;
#pragma unroll
  for (uint32_t q = 0; q < 4; ++q) {
    uint32_t c = (o0i + q) << 2;
    uint32_t best = 0, bi = 0;
#pragma unroll
    for (uint32_t ff = 0; ff < 4; ++ff) {
      uint32_t y0, y1;
      threefry(0u, c + ff, y0, y1);
      uint32_t m = (y0 ^ y1) >> 9;
      if (ff == 0) best = m;
      else if (m > best) { best = m; bi = ff; }
    }
    byte |= bi << (2 * q);
  }
  idx1[g * 256u + t] = (uint8_t)byte;

  {
    union { uint16_t h[8]; uint64_t q[2]; } p;
    p.h[0] = f2bf(v0.x); p.h[1] = f2bf(v0.y);
    p.h[2] = f2bf(v0.z); p.h[3] = f2bf(v0.w);
    p.h[4] = f2bf(v1.x); p.h[5] = f2bf(v1.y);
    p.h[6] = f2bf(v1.z); p.h[7] = f2bf(v1.w);
    uint64_t* dst = (uint64_t*)(xb + (size_t)f * B_DIM * K_DIM + xoff);
    dst[0] = p.q[0]; dst[1] = p.q[1];
  }

#pragma unroll
  for (int i = 0; i < 4; ++i) tile[ty + i * 8][tx] = wv[i];
  __syncthreads();
  {
    const int el = t >> 3, kc = (t & 7) * 4;
    union { uint16_t h[4]; uint64_t q; } p;
#pragma unroll
    for (int i = 0; i < 4; ++i) p.h[i] = f2bf(tile[kc + i][el]);
    uint16_t* dst = Wt + (size_t)f * E_DIM * K_DIM;
    *(uint64_t*)(dst + (size_t)(e0 + el) * K_DIM + k0 + kc) = p.q;
  }
}

__device__ __forceinline__ void async16(const uint16_t* g, uint16_t* lds) {
  __builtin_amdgcn_global_load_lds(
      (const __attribute__((address_space(1))) void*)g,
      (__attribute__((address_space(3))) void*)lds, 16, 0, 0);
}

#define PLANE_A ((size_t)B_DIM * K_DIM)
#define PLANE_B ((size_t)E_DIM * K_DIM)

#define PH_IN() do { \
    asm volatile("" ::: "memory"); \
    __builtin_amdgcn_s_barrier(); \
    asm volatile("s_waitcnt lgkmcnt(0)" ::: "memory"); \
    __builtin_amdgcn_sched_barrier(0); \
  } while (0)
#define PH_OUT() do { \
    asm volatile("" ::: "memory"); \
    __builtin_amdgcn_s_barrier(); \
    asm volatile("" ::: "memory"); \
  } while (0)

// 512 threads = 8 waves (2M x 4N of 128x64). BM=BN=256, BK=64, K=2048
// (2 planes). 32 K-tiles, 4 phases each, vmcnt(6) at tile boundaries.
__global__ __launch_bounds__(512, 2) void gemm_fused(
    const uint16_t* __restrict__ Ab, const uint16_t* __restrict__ Bbt,
    const uint32_t* __restrict__ idx2,
    const float* __restrict__ bias0, const float* __restrict__ bias1,
    const float* __restrict__ bias2, const float* __restrict__ bias3,
    float* __restrict__ out) {
  __shared__ uint16_t S[65536];  // 128 KiB: [buf][A/B][khalf][256 rows][4x8 u16]

  const int tid = threadIdx.x;
  const int l = tid & 63;
  const int w = tid >> 6;            // 0..7
  const int wr = w >> 2, wc = w & 3; // 2M x 4N
  const int fr = l & 15, fq = l >> 4;

  // 256 blocks: XCD-chunked bijective swizzle (8 x 32)
  const int flat = (int)blockIdx.x;
  const int swz = (flat & 7) * 32 + (flat >> 3);
  const int ks = swz >> 7;                 // plane pair 0/1
  const int mn = swz & 127;                // 16 M x 8 N
  const int mBase = (mn >> 3) * 256;
  const int nBase = (mn & 7) * 256;
  const int f0 = ks * 2;

  // ---- staging addressing (pre-swizzled global src, linear LDS dst) ----
  const int srow = tid >> 2;               // 0..127 (round adds 128)
  const int jp = (tid & 3) ^ ((tid >> 3) & 3);
  const size_t aSrc = (size_t)(mBase + srow) * K_DIM + jp * 8;
  const size_t bSrc = (size_t)(nBase + srow) * K_DIM + jp * 8;

  auto stage = [&](int tile, int bsel, int h) {
    if (tile >= 32) return;
    const int buf = tile & 1;
    const size_t po = (size_t)(f0 + (tile >> 4)) * (bsel ? PLANE_B : PLANE_A);
    const int ko = (tile & 15) * 64 + h * 32;
    const uint16_t* g0 = (bsel ? Bbt : Ab) + po + (bsel ? bSrc : aSrc) + ko;
    uint16_t* d = &S[buf * 32768 + bsel * 16384 + h * 8192 + tid * 8];
    async16(g0, d);
    async16(g0 + (size_t)128 * K_DIM, d + 4096);
  };

  // ---- read-side bases: slot = fq ^ ((row>>1)&3) = fq ^ ((fr>>1)&3) ----
  const int slot = fq ^ ((fr >> 1) & 3);
  const int aRdB = (wr * 128 + fr) * 32 + slot * 8;
  const int bRdB = (wc * 64 + fr) * 32 + slot * 8;

  // ---- selection words (packed: byte mi of iwp[ni][mi>>2] = 4 rows' sel) ----
  uint32_t iwp[4][2];
#pragma unroll
  for (int ni = 0; ni < 4; ++ni) {
    const int col = nBase + wc * 64 + ni * 16 + fr;
#pragma unroll
    for (int gq = 0; gq < 2; ++gq) {
      uint32_t pk = 0;
#pragma unroll
      for (int q = 0; q < 4; ++q) {
        uint32_t wd = idx2[(size_t)col * (B_DIM / 16) +
                           ((mBase + wr * 128) >> 4) + gq * 4 + q];
        pk |= ((wd >> (fq * 8)) & 0xFFu) << (q * 8);
      }
      iwp[ni][gq] = pk;
    }
  }
  const float* bpl0 = (f0 == 0) ? bias0 : bias2;
  const float* bpl1 = (f0 == 0) ? bias1 : bias3;
  float bz[2][4];
#pragma unroll
  for (int ni = 0; ni < 4; ++ni) {
    const int col = nBase + wc * 64 + ni * 16 + fr;
    bz[0][ni] = bpl0[col];
    bz[1][ni] = bpl1[col];
  }

  floatx4 acc[8][4] = {};

  auto fold = [&](int pf) {  // masked stores for plane f0+pf, reset acc
    const uint32_t fsel = (uint32_t)(f0 + pf);
#pragma unroll
    for (int ni = 0; ni < 4; ++ni) {
      const int col = nBase + wc * 64 + ni * 16 + fr;
      const float bv = bz[pf][ni];
#pragma unroll
      for (int mi = 0; mi < 8; ++mi) {
        const uint32_t byt = iwp[ni][mi >> 2] >> ((mi & 3) * 8);
        const int row0 = mBase + wr * 128 + mi * 16 + fq * 4;
#pragma unroll
        for (int r = 0; r < 4; ++r) {
          if (((byt >> (r * 2)) & 3u) == fsel) {
            float o = acc[mi][ni][r] + bv;
            __builtin_nontemporal_store(
                o > 0.f ? o : 0.f, &out[(size_t)(row0 + r) * E_DIM + col]);
          }
          acc[mi][ni][r] = 0.f;
        }
      }
    }
  };

  // ---- prologue: T0{B0,A0,B1,A1}, T1{B0,A0,B1}; vmcnt(6) => T0 complete ----
  stage(0, 1, 0); stage(0, 0, 0); stage(0, 1, 1); stage(0, 0, 1);
  stage(1, 1, 0); stage(1, 0, 0); stage(1, 1, 1);
  asm volatile("s_waitcnt vmcnt(6)" ::: "memory");
  __builtin_amdgcn_s_barrier();
  asm volatile("" ::: "memory");

#pragma unroll 1
  for (int jt = 0; jt < 32; ++jt) {
    const uint16_t* Sa = &S[(jt & 1) * 32768 + aRdB];
    const uint16_t* Sb = &S[(jt & 1) * 32768 + 16384 + bRdB];
    short8 a[4], b[4];

    // ---- q0: khalf0, mi 0-3 (reads b_h0[4] + a[4]); stage (jt+1, A, h1) ----
#pragma unroll
    for (int ni = 0; ni < 4; ++ni) b[ni] = *(const short8*)&Sb[ni * 512];
#pragma unroll
    for (int mi = 0; mi < 4; ++mi) a[mi] = *(const short8*)&Sa[mi * 512];
    stage(jt + 1, 0, 1);
    PH_IN();
    __builtin_amdgcn_s_setprio(1);
#pragma unroll
    for (int mi = 0; mi < 4; ++mi)
#pragma unroll
      for (int ni = 0; ni < 4; ++ni)
        acc[mi][ni] = __builtin_amdgcn_mfma_f32_16x16x32_bf16(
            a[mi], b[ni], acc[mi][ni], 0, 0, 0);
    __builtin_amdgcn_s_setprio(0);
    PH_OUT();

    // ---- q1: khalf0, mi 4-7 (reads a[4]; b cached); stage (jt+2, B, h0) ----
#pragma unroll
    for (int mi = 0; mi < 4; ++mi)
      a[mi] = *(const short8*)&Sa[(4 + mi) * 512];
    stage(jt + 2, 1, 0);
    PH_IN();
    __builtin_amdgcn_s_setprio(1);
#pragma unroll
    for (int mi = 0; mi < 4; ++mi)
#pragma unroll
      for (int ni = 0; ni < 4; ++ni)
        acc[4 + mi][ni] = __builtin_amdgcn_mfma_f32_16x16x32_bf16(
            a[mi], b[ni], acc[4 + mi][ni], 0, 0, 0);
    __builtin_amdgcn_s_setprio(0);
    PH_OUT();

    // ---- q2: khalf1, mi 0-3 (reads b_h1[4] + a[4]); stage (jt+2, A, h0) ----
#pragma unroll
    for (int ni = 0; ni < 4; ++ni)
      b[ni] = *(const short8*)&Sb[8192 + ni * 512];
#pragma unroll
    for (int mi = 0; mi < 4; ++mi)
      a[mi] = *(const short8*)&Sa[8192 + mi * 512];
    stage(jt + 2, 0, 0);
    PH_IN();
    __builtin_amdgcn_s_setprio(1);
#pragma unroll
    for (int mi = 0; mi < 4; ++mi)
#pragma unroll
      for (int ni = 0; ni < 4; ++ni)
        acc[mi][ni] = __builtin_amdgcn_mfma_f32_16x16x32_bf16(
            a[mi], b[ni], acc[mi][ni], 0, 0, 0);
    __builtin_amdgcn_s_setprio(0);
    PH_OUT();

    // ---- q3: khalf1, mi 4-7 (reads a[4]); stage (jt+2, B, h1) ----
#pragma unroll
    for (int mi = 0; mi < 4; ++mi)
      a[mi] = *(const short8*)&Sa[8192 + (4 + mi) * 512];
    stage(jt + 2, 1, 1);
    PH_IN();
    __builtin_amdgcn_s_setprio(1);
#pragma unroll
    for (int mi = 0; mi < 4; ++mi)
#pragma unroll
      for (int ni = 0; ni < 4; ++ni)
        acc[4 + mi][ni] = __builtin_amdgcn_mfma_f32_16x16x32_bf16(
            a[mi], b[ni], acc[4 + mi][ni], 0, 0, 0);
    __builtin_amdgcn_s_setprio(0);

    if (jt == 15) fold(0);           // plane f0 done: masked stores, acc=0
    if (jt == 31) {
      fold(1);                       // plane f0+1: final stores
    } else {
      // boundary: 3 newest half-tiles may fly; (jt,q0)'s (jt+1,A,h1) must land
      if (jt <= 29) asm volatile("s_waitcnt vmcnt(6)" ::: "memory");
      else          asm volatile("s_waitcnt vmcnt(0)" ::: "memory");
      PH_OUT();
    }
  }
}

extern "C" void kernel_launch(void* const* d_in, const int* in_sizes, int n_in,
                              void* d_out, int out_size, void* d_ws, size_t ws_size,
                              hipStream_t stream) {
  const float* x[4]; const float* W[4]; const float* bs[4];
  for (int f = 0; f < 4; ++f) {
    x[f]  = (const float*)d_in[3 * f + 0];
    W[f]  = (const float*)d_in[3 * f + 1];
    bs[f] = (const float*)d_in[3 * f + 2];
  }
  char* ws = (char*)d_ws;
  uint16_t* xb  = (uint16_t*)ws;                               // 32 MB
  uint16_t* Wt  = (uint16_t*)(ws + (size_t)32 * 1024 * 1024);  // 16 MB
  uint8_t*  idx1 = (uint8_t*)(ws + (size_t)48 * 1024 * 1024);  //  2 MB
  float* out = (float*)d_out;

  prep_kernel<<<dim3(8192), dim3(256), 0, stream>>>(
      x[0], x[1], x[2], x[3], W[0], W[1], W[2], W[3], xb, Wt, idx1);
  gemm_fused<<<dim3(256), dim3(512), 0, stream>>>(
      xb, Wt, (const uint32_t*)idx1, bs[0], bs[1], bs[2], bs[3], out);
}

// Round 6
// 369.826 us; speedup vs baseline: 1.0490x; 1.0490x over previous
//
#include <hip/hip_runtime.h>
#include <stdint.h>

// ---------------------------------------------------------------------------
// EmbraceNet fused: out[b,e] = relu(x_f @ W_f + b_f)[b,e],  f = idx[b,e]
// idx = categorical(key=42): partitionable threefry, bits = y0^y1 of
// threefry2x32((0,42), (0, (e*4096+b)*4+f)); argmax over bits>>9, strict >.
// PASS since R4 (absmax 0.031).
//
// R16 == R15 resubmitted (R15 bench was GPUAcquisitionTimeout -- infra, no
// kernel verdict; OOB/barrier/vmcnt audit clean).
// R15: R14 post-mortem -- schedule CORRECT (passed), but K-split's masked
// scatter stores caused 8x write amplification (WRITE 271MB, RMW FETCH
// +100MB) = memory-bound at 2 TB/s. Fix: drop K-split, keep the verified
// quarter-rotation schedule. BM=128 x BN=256, 8 waves (2Mx4N) of 64x64
// -> acc[4][4]+res[4][4] fit in regs; fold = R10's register-only selection
// fold (NO mid-loop stores, vmcnt stream stays pure); final dense store =
// R10's verified epilogue. K=4096 (4 planes), 64 tiles x 2 phases (khalf).
// Per phase: {8 ds_read_b128 -> stage quarter-pair (3 gload_lds) ->
// barrier -> lgkmcnt(0)+sched_barrier -> setprio 16 MFMA -> vmcnt(6) ->
// barrier}. Rotation: P(jt,h0) stages (jt+1,h1) [other buf, freed 1 phase
// ago]; P(jt,h1) stages (jt+2,h0) [cur buf h0, freed last phase]. Each
// staged quarter lands >=2 phases before use; vmcnt(6) = 2 stage-pairs in
// flight; tail 6/3/0. LDS 96 KiB (2 x {A 128x64, B 256x64} bf16, khalf-
// split rows of 4x16B slots, slot = fq ^ ((row>>1)&3), 2 lanes/slot-pos
// = conflict-free). MFMA cost recalibrated: 16x16x32 ~= 16 cyc/SIMD
// (m06) -> floor 27.5 us; R10 at 30% of that pipe.
// ---------------------------------------------------------------------------

typedef short short8 __attribute__((ext_vector_type(8)));
typedef float floatx4 __attribute__((ext_vector_type(4)));

#define B_DIM 4096
#define K_DIM 1024
#define E_DIM 2048

__device__ __forceinline__ uint32_t rotl32(uint32_t x, uint32_t r) {
  return __builtin_amdgcn_alignbit(x, x, 32u - r);
}

__device__ __forceinline__ uint16_t f2bf(float x) {
  uint32_t u = __float_as_uint(x);
  u += 0x7FFFu + ((u >> 16) & 1u);
  return (uint16_t)(u >> 16);
}

// JAX threefry2x32, key = (0, 42)
__device__ __forceinline__ void threefry(uint32_t x0, uint32_t x1,
                                         uint32_t& o0, uint32_t& o1) {
  const uint32_t ks0 = 0u;
  const uint32_t ks1 = 42u;
  const uint32_t ks2 = 0x1BD11BDAu ^ 42u;
  x0 += ks0; x1 += ks1;
#define TF_R(r) { x0 += x1; x1 = rotl32(x1, r); x1 ^= x0; }
  TF_R(13) TF_R(15) TF_R(26) TF_R(6)
  x0 += ks1; x1 += ks2 + 1u;
  TF_R(17) TF_R(29) TF_R(16) TF_R(24)
  x0 += ks2; x1 += ks0 + 2u;
  TF_R(13) TF_R(15) TF_R(26) TF_R(6)
  x0 += ks0; x1 += ks1 + 3u;
  TF_R(17) TF_R(29) TF_R(16) TF_R(24)
  x0 += ks1; x1 += ks2 + 4u;
  TF_R(13) TF_R(15) TF_R(26) TF_R(6)
  x0 += ks2; x1 += ks0 + 5u;
#undef TF_R
  o0 = x0; o1 = x1;
}

// 8192 blocks x 256 threads. Unchanged since R10 (verified).
__global__ __launch_bounds__(256) void prep_kernel(
    const float* __restrict__ x0, const float* __restrict__ x1,
    const float* __restrict__ x2, const float* __restrict__ x3,
    const float* __restrict__ W0, const float* __restrict__ W1,
    const float* __restrict__ W2, const float* __restrict__ W3,
    uint16_t* __restrict__ xb, uint16_t* __restrict__ Wt,
    uint8_t* __restrict__ idx1) {
  __shared__ float tile[32][33];
  const uint32_t g = blockIdx.x;       // 0..8191
  const int t = threadIdx.x;
  const int f = g >> 11;               // plane 0..3
  const uint32_t ip = g & 2047u;       // tile/chunk within plane

  const float* x = (f == 0) ? x0 : (f == 1) ? x1 : (f == 2) ? x2 : x3;
  const size_t xoff = ((size_t)ip * 256 + t) * 8;
  float4 v0 = *(const float4*)(x + xoff);
  float4 v1 = *(const float4*)(x + xoff + 4);

  const float* W = (f == 0) ? W0 : (f == 1) ? W1 : (f == 2) ? W2 : W3;
  const int e0 = (int)(ip & 63) * 32, k0 = (int)(ip >> 6) * 32;
  const int tx = t & 31, ty = t >> 5;
  float wv[4];
#pragma unroll
  for (int i = 0; i < 4; ++i)
    wv[i] = W[(size_t)(k0 + ty + i * 8) * E_DIM + e0 + tx];

  const uint32_t o0i = (g * 256u + t) * 4u;
  uint32_t byte = 0;
#pragma unroll
  for (uint32_t q = 0; q < 4; ++q) {
    uint32_t c = (o0i + q) << 2;
    uint32_t best = 0, bi = 0;
#pragma unroll
    for (uint32_t ff = 0; ff < 4; ++ff) {
      uint32_t y0, y1;
      threefry(0u, c + ff, y0, y1);
      uint32_t m = (y0 ^ y1) >> 9;
      if (ff == 0) best = m;
      else if (m > best) { best = m; bi = ff; }
    }
    byte |= bi << (2 * q);
  }
  idx1[g * 256u + t] = (uint8_t)byte;

  {
    union { uint16_t h[8]; uint64_t q[2]; } p;
    p.h[0] = f2bf(v0.x); p.h[1] = f2bf(v0.y);
    p.h[2] = f2bf(v0.z); p.h[3] = f2bf(v0.w);
    p.h[4] = f2bf(v1.x); p.h[5] = f2bf(v1.y);
    p.h[6] = f2bf(v1.z); p.h[7] = f2bf(v1.w);
    uint64_t* dst = (uint64_t*)(xb + (size_t)f * B_DIM * K_DIM + xoff);
    dst[0] = p.q[0]; dst[1] = p.q[1];
  }

#pragma unroll
  for (int i = 0; i < 4; ++i) tile[ty + i * 8][tx] = wv[i];
  __syncthreads();
  {
    const int el = t >> 3, kc = (t & 7) * 4;
    union { uint16_t h[4]; uint64_t q; } p;
#pragma unroll
    for (int i = 0; i < 4; ++i) p.h[i] = f2bf(tile[kc + i][el]);
    uint16_t* dst = Wt + (size_t)f * E_DIM * K_DIM;
    *(uint64_t*)(dst + (size_t)(e0 + el) * K_DIM + k0 + kc) = p.q;
  }
}

__device__ __forceinline__ void async16(const uint16_t* g, uint16_t* lds) {
  __builtin_amdgcn_global_load_lds(
      (const __attribute__((address_space(1))) void*)g,
      (__attribute__((address_space(3))) void*)lds, 16, 0, 0);
}

#define PLANE_A ((size_t)B_DIM * K_DIM)
#define PLANE_B ((size_t)E_DIM * K_DIM)

#define PH_IN() do { \
    asm volatile("" ::: "memory"); \
    __builtin_amdgcn_s_barrier(); \
    asm volatile("s_waitcnt lgkmcnt(0)" ::: "memory"); \
    __builtin_amdgcn_sched_barrier(0); \
  } while (0)

// Per-buffer LDS layout (u16 units), buf stride 24576 (48 KiB):
//   A.h0 [0,4096)  A.h1 [4096,8192)  B.h0 [8192,16384)  B.h1 [16384,24576)
// Row = 32 bf16 (64 B) = 4 slots x 8 elems; slot = chunk ^ ((row>>1)&3).
__global__ __launch_bounds__(512, 2) void gemm_fused(
    const uint16_t* __restrict__ Ab, const uint16_t* __restrict__ Bbt,
    const uint32_t* __restrict__ idx2,
    const float* __restrict__ bias0, const float* __restrict__ bias1,
    const float* __restrict__ bias2, const float* __restrict__ bias3,
    float* __restrict__ out) {
  __shared__ uint16_t S[49152];  // 96 KiB

  const int tid = threadIdx.x;
  const int l = tid & 63;
  const int w = tid >> 6;            // 0..7
  const int wr = w >> 2, wc = w & 3; // 2M x 4N of 64x64
  const int fr = l & 15, fq = l >> 4;

  // 256 blocks = 8 XCDs x 32, bijective chunked swizzle
  const int flat = (int)blockIdx.x;
  const int swz = (flat & 7) * 32 + (flat >> 3);
  const int mBase = (swz >> 3) * 128;   // 32 M-tiles
  const int nBase = (swz & 7) * 256;    // 8 N-tiles

  // ---- staging addressing (pre-swizzled global src, linear LDS dst) ----
  const int srow = tid >> 2;                       // 0..127
  const int jp = (tid & 3) ^ ((tid >> 3) & 3);     // swizzled k-chunk
  const size_t aSrc = (size_t)(mBase + srow) * K_DIM + jp * 8;
  const size_t bSrc = (size_t)(nBase + srow) * K_DIM + jp * 8;

  // stage quarter-pair {A.h, B.h} of tile t (3 loads); buf = t&1
  auto stage = [&](int t, int h) {
    if (t >= 64) return;
    const int f = t >> 4;
    const int ko = (t & 15) * 64 + h * 32;
    const int bb = (t & 1) * 24576;
    const uint16_t* gA = Ab + (size_t)f * PLANE_A + aSrc + ko;
    const uint16_t* gB = Bbt + (size_t)f * PLANE_B + bSrc + ko;
    async16(gA, &S[bb + h * 4096 + tid * 8]);
    uint16_t* dB = &S[bb + 8192 + h * 8192 + tid * 8];
    async16(gB, dB);
    async16(gB + (size_t)128 * K_DIM, dB + 4096);
  };

  // ---- read-side: slot = fq ^ ((fr>>1)&3) (row bits 1:0 == fr bits) ----
  const int slot = fq ^ ((fr >> 1) & 3);
  const int aRd = (wr * 64 + fr) * 32 + slot * 8;   // + mi*512
  const int bRd = (wc * 64 + fr) * 32 + slot * 8;   // + ni*512

  // ---- selection words + bias in regs (vmcnt stream stays pure) ----
  const int b_hi0 = (mBase + wr * 64) >> 4;
  uint32_t iw[4][4];
#pragma unroll
  for (int ni = 0; ni < 4; ++ni) {
    int col = nBase + wc * 64 + ni * 16 + fr;
#pragma unroll
    for (int mi = 0; mi < 4; ++mi)
      iw[ni][mi] = idx2[(size_t)col * (B_DIM / 16) + b_hi0 + mi];
  }
  float bz0[4], bz1[4], bz2[4], bz3[4];
#pragma unroll
  for (int ni = 0; ni < 4; ++ni) {
    int col = nBase + wc * 64 + ni * 16 + fr;
    bz0[ni] = bias0[col]; bz1[ni] = bias1[col];
    bz2[ni] = bias2[col]; bz3[ni] = bias3[col];
  }

  floatx4 acc[4][4] = {};
  floatx4 res[4][4] = {};

  // register-only selection fold (R10-verified), f inlined per call site
  auto fold = [&](int f) {
#pragma unroll
    for (int ni = 0; ni < 4; ++ni) {
      float bv = (f == 0) ? bz0[ni] : (f == 1) ? bz1[ni]
               : (f == 2) ? bz2[ni] : bz3[ni];
#pragma unroll
      for (int mi = 0; mi < 4; ++mi) {
        uint32_t wd = iw[ni][mi];
#pragma unroll
        for (int r = 0; r < 4; ++r) {
          uint32_t sel = (wd >> (2 * (fq * 4 + r))) & 3u;
          if (sel == (uint32_t)f) res[mi][ni][r] = acc[mi][ni][r] + bv;
          acc[mi][ni][r] = 0.f;
        }
      }
    }
  };

  // ---- prologue: stage(0,h0), (0,h1), (1,h0); vmcnt(6) => 0.h0 landed ----
  stage(0, 0);
  stage(0, 1);
  stage(1, 0);
  asm volatile("s_waitcnt vmcnt(6)" ::: "memory");
  __builtin_amdgcn_s_barrier();
  asm volatile("" ::: "memory");

#pragma unroll 1
  for (int jt = 0; jt < 64; ++jt) {
    const int bb = (jt & 1) * 24576;
    short8 a[4], b[4];

    // ===== phase h0: read {A.h0, B.h0}; stage (jt+1, h1) =====
#pragma unroll
    for (int mi = 0; mi < 4; ++mi)
      a[mi] = *(const short8*)&S[bb + aRd + mi * 512];
#pragma unroll
    for (int ni = 0; ni < 4; ++ni)
      b[ni] = *(const short8*)&S[bb + 8192 + bRd + ni * 512];
    stage(jt + 1, 1);
    PH_IN();
    __builtin_amdgcn_s_setprio(1);
#pragma unroll
    for (int mi = 0; mi < 4; ++mi)
#pragma unroll
      for (int ni = 0; ni < 4; ++ni)
        acc[mi][ni] = __builtin_amdgcn_mfma_f32_16x16x32_bf16(
            a[mi], b[ni], acc[mi][ni], 0, 0, 0);
    __builtin_amdgcn_s_setprio(0);
    if (jt < 63) asm volatile("s_waitcnt vmcnt(6)" ::: "memory");
    else         asm volatile("s_waitcnt vmcnt(0)" ::: "memory");
    asm volatile("" ::: "memory");
    __builtin_amdgcn_s_barrier();
    asm volatile("" ::: "memory");

    // ===== phase h1: read {A.h1, B.h1}; stage (jt+2, h0) =====
#pragma unroll
    for (int mi = 0; mi < 4; ++mi)
      a[mi] = *(const short8*)&S[bb + 4096 + aRd + mi * 512];
#pragma unroll
    for (int ni = 0; ni < 4; ++ni)
      b[ni] = *(const short8*)&S[bb + 16384 + bRd + ni * 512];
    stage(jt + 2, 0);
    PH_IN();
    __builtin_amdgcn_s_setprio(1);
#pragma unroll
    for (int mi = 0; mi < 4; ++mi)
#pragma unroll
      for (int ni = 0; ni < 4; ++ni)
        acc[mi][ni] = __builtin_amdgcn_mfma_f32_16x16x32_bf16(
            a[mi], b[ni], acc[mi][ni], 0, 0, 0);
    __builtin_amdgcn_s_setprio(0);

    if (jt == 15) fold(0);
    if (jt == 31) fold(1);
    if (jt == 47) fold(2);

    if (jt < 63) {
      if (jt <= 61) asm volatile("s_waitcnt vmcnt(6)" ::: "memory");
      else          asm volatile("s_waitcnt vmcnt(3)" ::: "memory");
      asm volatile("" ::: "memory");
      __builtin_amdgcn_s_barrier();
      asm volatile("" ::: "memory");
    }
  }

  fold(3);

  // dense coalesced store with relu. C/D: col=lane&15, row=(lane>>4)*4+reg
#pragma unroll
  for (int ni = 0; ni < 4; ++ni) {
    int col = nBase + wc * 64 + ni * 16 + fr;
#pragma unroll
    for (int mi = 0; mi < 4; ++mi) {
      int row0 = mBase + wr * 64 + mi * 16 + fq * 4;
#pragma unroll
      for (int r = 0; r < 4; ++r) {
        float o = res[mi][ni][r];
        __builtin_nontemporal_store(o > 0.f ? o : 0.f,
                                    &out[(size_t)(row0 + r) * E_DIM + col]);
      }
    }
  }
}

extern "C" void kernel_launch(void* const* d_in, const int* in_sizes, int n_in,
                              void* d_out, int out_size, void* d_ws, size_t ws_size,
                              hipStream_t stream) {
  const float* x[4]; const float* W[4]; const float* bs[4];
  for (int f = 0; f < 4; ++f) {
    x[f]  = (const float*)d_in[3 * f + 0];
    W[f]  = (const float*)d_in[3 * f + 1];
    bs[f] = (const float*)d_in[3 * f + 2];
  }
  char* ws = (char*)d_ws;
  uint16_t* xb  = (uint16_t*)ws;                               // 32 MB
  uint16_t* Wt  = (uint16_t*)(ws + (size_t)32 * 1024 * 1024);  // 16 MB
  uint8_t*  idx1 = (uint8_t*)(ws + (size_t)48 * 1024 * 1024);  //  2 MB
  float* out = (float*)d_out;

  prep_kernel<<<dim3(8192), dim3(256), 0, stream>>>(
      x[0], x[1], x[2], x[3], W[0], W[1], W[2], W[3], xb, Wt, idx1);
  gemm_fused<<<dim3(256), dim3(512), 0, stream>>>(
      xb, Wt, (const uint32_t*)idx1, bs[0], bs[1], bs[2], bs[3], out);
}

// Round 7
// 252.793 us; speedup vs baseline: 1.5347x; 1.4630x over previous
//
#include <hip/hip_runtime.h>
#include <stdint.h>

// ---------------------------------------------------------------------------
// EmbraceNet fused: out[b,e] = relu(x_f @ W_f + b_f)[b,e],  f = idx[b,e]
// idx = categorical(key=42): partitionable threefry, bits = y0^y1 of
// threefry2x32((0,42), (0, (e*4096+b)*4+f)); argmax over bits>>9, strict >.
// PASS since R4 (absmax 0.031).
//
// R17: REVERT to R10-exact gemm (92.5 us; best of 5 structural variants:
// counted-vmcnt x3 and phase-split x2 all regressed -- R11 104, R13 110,
// R14 228, R16 212 us; R16 additionally showed spill-signature WRITE
// 128MB at 1 blk/CU). Single added lever, never tested on this structure:
// bijective XCD-chunked block swizzle (T1), 512 blocks = 8 XCDs x 64
// contiguous tiles -> neighboring tiles share A/B panels within one
// XCD's L2 (R10 FETCH 140MB vs ~50MB ideal = cross-XCD re-fetch).
// Everything else verbatim R10: 128x128 tile, 4 waves (2x2 of 64x64),
// BK=64 double-buffered LDS (64 KiB -> 2 blk/CU), one __syncthreads per
// 64-K iter, XOR k-chunk swizzle (row&7) on global source, register
// selection-fold at plane boundaries, dense coalesced epilogue.
// ---------------------------------------------------------------------------

typedef short short8 __attribute__((ext_vector_type(8)));
typedef float floatx4 __attribute__((ext_vector_type(4)));

#define B_DIM 4096
#define K_DIM 1024
#define E_DIM 2048

__device__ __forceinline__ uint32_t rotl32(uint32_t x, uint32_t r) {
  return __builtin_amdgcn_alignbit(x, x, 32u - r);
}

__device__ __forceinline__ uint16_t f2bf(float x) {
  uint32_t u = __float_as_uint(x);
  u += 0x7FFFu + ((u >> 16) & 1u);
  return (uint16_t)(u >> 16);
}

// JAX threefry2x32, key = (0, 42)
__device__ __forceinline__ void threefry(uint32_t x0, uint32_t x1,
                                         uint32_t& o0, uint32_t& o1) {
  const uint32_t ks0 = 0u;
  const uint32_t ks1 = 42u;
  const uint32_t ks2 = 0x1BD11BDAu ^ 42u;
  x0 += ks0; x1 += ks1;
#define TF_R(r) { x0 += x1; x1 = rotl32(x1, r); x1 ^= x0; }
  TF_R(13) TF_R(15) TF_R(26) TF_R(6)
  x0 += ks1; x1 += ks2 + 1u;
  TF_R(17) TF_R(29) TF_R(16) TF_R(24)
  x0 += ks2; x1 += ks0 + 2u;
  TF_R(13) TF_R(15) TF_R(26) TF_R(6)
  x0 += ks0; x1 += ks1 + 3u;
  TF_R(17) TF_R(29) TF_R(16) TF_R(24)
  x0 += ks1; x1 += ks2 + 4u;
  TF_R(13) TF_R(15) TF_R(26) TF_R(6)
  x0 += ks2; x1 += ks0 + 5u;
#undef TF_R
  o0 = x0; o1 = x1;
}

// 8192 blocks x 256 threads. Every thread: issue x loads (8 floats) + W
// loads (4 floats), crunch 4 idx outputs (16 threefry) while loads fly,
// then store x bf16 (16B), idx byte, and W transposed tile via LDS.
__global__ __launch_bounds__(256) void prep_kernel(
    const float* __restrict__ x0, const float* __restrict__ x1,
    const float* __restrict__ x2, const float* __restrict__ x3,
    const float* __restrict__ W0, const float* __restrict__ W1,
    const float* __restrict__ W2, const float* __restrict__ W3,
    uint16_t* __restrict__ xb, uint16_t* __restrict__ Wt,
    uint8_t* __restrict__ idx1) {
  __shared__ float tile[32][33];
  const uint32_t g = blockIdx.x;       // 0..8191
  const int t = threadIdx.x;
  const int f = g >> 11;               // plane 0..3
  const uint32_t ip = g & 2047u;       // tile/chunk within plane

  // ---- issue x loads: plane f, 8 consecutive floats per thread ----
  const float* x = (f == 0) ? x0 : (f == 1) ? x1 : (f == 2) ? x2 : x3;
  const size_t xoff = ((size_t)ip * 256 + t) * 8;
  float4 v0 = *(const float4*)(x + xoff);
  float4 v1 = *(const float4*)(x + xoff + 4);

  // ---- issue W loads: 32x32 tile ip of plane f ----
  const float* W = (f == 0) ? W0 : (f == 1) ? W1 : (f == 2) ? W2 : W3;
  const int e0 = (int)(ip & 63) * 32, k0 = (int)(ip >> 6) * 32;
  const int tx = t & 31, ty = t >> 5;
  float wv[4];
#pragma unroll
  for (int i = 0; i < 4; ++i)
    wv[i] = W[(size_t)(k0 + ty + i * 8) * E_DIM + e0 + tx];

  // ---- threefry crunch: outputs o0..o0+3, pack 2 bits each ----
  const uint32_t o0i = (g * 256u + t) * 4u;
  uint32_t byte = 0;
#pragma unroll
  for (uint32_t q = 0; q < 4; ++q) {
    uint32_t c = (o0i + q) << 2;
    uint32_t best = 0, bi = 0;
#pragma unroll
    for (uint32_t ff = 0; ff < 4; ++ff) {
      uint32_t y0, y1;
      threefry(0u, c + ff, y0, y1);
      uint32_t m = (y0 ^ y1) >> 9;
      if (ff == 0) best = m;
      else if (m > best) { best = m; bi = ff; }
    }
    byte |= bi << (2 * q);
  }
  idx1[g * 256u + t] = (uint8_t)byte;

  // ---- x store: 8 bf16 = 16B ----
  {
    union { uint16_t h[8]; uint64_t q[2]; } p;
    p.h[0] = f2bf(v0.x); p.h[1] = f2bf(v0.y);
    p.h[2] = f2bf(v0.z); p.h[3] = f2bf(v0.w);
    p.h[4] = f2bf(v1.x); p.h[5] = f2bf(v1.y);
    p.h[6] = f2bf(v1.z); p.h[7] = f2bf(v1.w);
    uint64_t* dst = (uint64_t*)(xb + (size_t)f * B_DIM * K_DIM + xoff);
    dst[0] = p.q[0]; dst[1] = p.q[1];
  }

  // ---- W transpose via LDS ----
#pragma unroll
  for (int i = 0; i < 4; ++i) tile[ty + i * 8][tx] = wv[i];
  __syncthreads();
  {
    const int el = t >> 3, kc = (t & 7) * 4;
    union { uint16_t h[4]; uint64_t q; } p;
#pragma unroll
    for (int i = 0; i < 4; ++i) p.h[i] = f2bf(tile[kc + i][el]);
    uint16_t* dst = Wt + (size_t)f * E_DIM * K_DIM;
    *(uint64_t*)(dst + (size_t)(e0 + el) * K_DIM + k0 + kc) = p.q;
  }
}

__device__ __forceinline__ void async16(const uint16_t* g, uint16_t* lds) {
  __builtin_amdgcn_global_load_lds(
      (const __attribute__((address_space(1))) void*)g,
      (__attribute__((address_space(3))) void*)lds, 16, 0, 0);
}

// 256 threads (4 waves, 2x2 of 64x64), 128x128 tile, BK=64, f-loop inside,
// double-buffered LDS (64KB), one barrier per 64-K iter (64 total).
// LDS[row][pos] holds global k-chunk pos^(row&7) (XOR swizzle, 8x16B chunks).
__global__ __launch_bounds__(256, 2) void gemm_fused(
    const uint16_t* __restrict__ Ab, const uint16_t* __restrict__ Bbt,
    const uint32_t* __restrict__ idx2,
    const float* __restrict__ bias0, const float* __restrict__ bias1,
    const float* __restrict__ bias2, const float* __restrict__ bias3,
    float* __restrict__ out) {
  __shared__ uint16_t As[2][128 * 64];
  __shared__ uint16_t Bs[2][128 * 64];

  const int tid = threadIdx.x;
  const int w = tid >> 6;        // 0..3
  const int l = tid & 63;

  // R17: bijective XCD-chunked swizzle. 512 blocks = 8 XCDs x 64
  // contiguous tiles (m-major within chunk -> A panels L2-resident).
  const int flat = (int)(blockIdx.y * gridDim.x + blockIdx.x);
  const int swz = (flat & 7) * 64 + (flat >> 3);
  const int mBase = (swz >> 4) * 128;   // 32 m-tiles
  const int nBase = (swz & 15) * 128;   // 16 n-tiles

  const int wm = (w >> 1) * 64, wn = (w & 1) * 64;
  // staging: chunk c (8 rows of 64k); lane -> row sr, swizzled k-chunk
  const int sr = l >> 3;                 // 0..7 row within chunk
  const int skc = ((l & 7) ^ sr) * 8;    // global k-elem offset (swizzled)
  const int fr = l & 15, fq = l >> 4;

  const int b_hi0 = (mBase + wm) >> 4;
  uint32_t iw[4][4];
#pragma unroll
  for (int ni = 0; ni < 4; ++ni) {
    int col = nBase + wn + ni * 16 + fr;
#pragma unroll
    for (int mi = 0; mi < 4; ++mi)
      iw[ni][mi] = idx2[(size_t)col * (B_DIM / 16) + b_hi0 + mi];
  }

  floatx4 res[4][4] = {};

#pragma unroll 1
  for (int f = 0; f < 4; ++f) {
    const uint16_t* A = Ab  + (size_t)f * B_DIM * K_DIM + (size_t)mBase * K_DIM;
    const uint16_t* B = Bbt + (size_t)f * E_DIM * K_DIM + (size_t)nBase * K_DIM;
    // wave w stages chunks 4w..4w+3 of each matrix (chunk = 8 rows x 64 k)
    const uint16_t* Aw = A + (size_t)(32 * w + sr) * K_DIM + skc;
    const uint16_t* Bw = B + (size_t)(32 * w + sr) * K_DIM + skc;

    floatx4 acc[4][4] = {};

#pragma unroll
    for (int tt = 0; tt < 4; ++tt) {
      async16(Aw + (size_t)(8 * tt) * K_DIM, &As[0][(4 * w + tt) * 512]);
      async16(Bw + (size_t)(8 * tt) * K_DIM, &Bs[0][(4 * w + tt) * 512]);
    }
    __syncthreads();

    int buf = 0;
#pragma unroll 1
    for (int kt = 0; kt < 16; ++kt) {
      int kn = (kt + 1) * 64;
      if (kt + 1 < 16) {  // next 64-K tile into other buffer, before compute
#pragma unroll
        for (int tt = 0; tt < 4; ++tt) {
          async16(Aw + (size_t)(8 * tt) * K_DIM + kn, &As[buf ^ 1][(4 * w + tt) * 512]);
          async16(Bw + (size_t)(8 * tt) * K_DIM + kn, &Bs[buf ^ 1][(4 * w + tt) * 512]);
        }
      }
#pragma unroll
      for (int h = 0; h < 2; ++h) {
        short8 a[4], b[4];
        const int ch = h * 4 + fq;
#pragma unroll
        for (int mi = 0; mi < 4; ++mi) {
          int row = wm + mi * 16 + fr;
          a[mi] = *(const short8*)&As[buf][row * 64 + (ch ^ (fr & 7)) * 8];
        }
#pragma unroll
        for (int ni = 0; ni < 4; ++ni) {
          int row = wn + ni * 16 + fr;
          b[ni] = *(const short8*)&Bs[buf][row * 64 + (ch ^ (fr & 7)) * 8];
        }
#pragma unroll
        for (int mi = 0; mi < 4; ++mi)
#pragma unroll
          for (int ni = 0; ni < 4; ++ni)
            acc[mi][ni] = __builtin_amdgcn_mfma_f32_16x16x32_bf16(
                a[mi], b[ni], acc[mi][ni], 0, 0, 0);
      }
      __syncthreads();
      buf ^= 1;
    }

    const float* bias = (f == 0) ? bias0 : (f == 1) ? bias1
                      : (f == 2) ? bias2 : bias3;
#pragma unroll
    for (int ni = 0; ni < 4; ++ni) {
      float bvf = bias[nBase + wn + ni * 16 + fr];
#pragma unroll
      for (int mi = 0; mi < 4; ++mi) {
        uint32_t wd = iw[ni][mi];
#pragma unroll
        for (int r = 0; r < 4; ++r) {
          uint32_t sel = (wd >> (2 * (fq * 4 + r))) & 3u;
          if (sel == (uint32_t)f) res[mi][ni][r] = acc[mi][ni][r] + bvf;
        }
      }
    }
  }

  // dense coalesced store with relu. C/D: col=lane&15, row=(lane>>4)*4+reg
#pragma unroll
  for (int ni = 0; ni < 4; ++ni) {
    int col = nBase + wn + ni * 16 + fr;
#pragma unroll
    for (int mi = 0; mi < 4; ++mi) {
      int row0 = mBase + wm + mi * 16 + fq * 4;
#pragma unroll
      for (int r = 0; r < 4; ++r) {
        float o = res[mi][ni][r];
        __builtin_nontemporal_store(o > 0.f ? o : 0.f,
                                    &out[(size_t)(row0 + r) * E_DIM + col]);
      }
    }
  }
}

extern "C" void kernel_launch(void* const* d_in, const int* in_sizes, int n_in,
                              void* d_out, int out_size, void* d_ws, size_t ws_size,
                              hipStream_t stream) {
  const float* x[4]; const float* W[4]; const float* bs[4];
  for (int f = 0; f < 4; ++f) {
    x[f]  = (const float*)d_in[3 * f + 0];
    W[f]  = (const float*)d_in[3 * f + 1];
    bs[f] = (const float*)d_in[3 * f + 2];
  }
  char* ws = (char*)d_ws;
  uint16_t* xb  = (uint16_t*)ws;                               // 32 MB
  uint16_t* Wt  = (uint16_t*)(ws + (size_t)32 * 1024 * 1024);  // 16 MB
  uint8_t*  idx1 = (uint8_t*)(ws + (size_t)48 * 1024 * 1024);  //  2 MB
  float* out = (float*)d_out;

  prep_kernel<<<dim3(8192), dim3(256), 0, stream>>>(
      x[0], x[1], x[2], x[3], W[0], W[1], W[2], W[3], xb, Wt, idx1);
  gemm_fused<<<dim3(E_DIM / 128, B_DIM / 128), dim3(256), 0, stream>>>(
      xb, Wt, (const uint32_t*)idx1, bs[0], bs[1], bs[2], bs[3], out);
}